// Round 1
// baseline (157.059 us; speedup 1.0000x reference)
//
#include <hip/hip_runtime.h>
#include <math.h>

// Problem constants (fixed by reference): B=2, C=64, H=W=128, N=9, KS=3, PAD=1
// out[b,o,i,j] = sum_{c,n} w_conv[o,c,n] * xs[b,c,n,i,j] * m[b,n,i,j]
// where xs = bilinear(x_pad, p2), p2/m derived from offset conv + depth bilinear.

#define HH 128
#define WW 128
#define CC 64
#define BB 2
#define STR 148   // LDS row stride (floats) for 144-float K-tiles, 16B aligned, bank-spread

// ---------------- kernel T: x (B,C,H,W) -> xT (B,H,W,C) ----------------
__global__ __launch_bounds__(256) void k_transpose(const float* __restrict__ x,
                                                   float* __restrict__ xT) {
    int idx = blockIdx.x * 256 + threadIdx.x;      // B*H*W*16 = 524288 threads
    int cq = idx & 15;                             // channel quad
    int pid = idx >> 4;                            // 0..32767 (b,i,j)
    int b = pid >> 14;
    int base = pid & 16383;                        // i*128+j
    const float* xp = x + (size_t)(b * 64 + cq * 4) * 16384 + base;
    float4 v;
    v.x = xp[0];
    v.y = xp[16384];
    v.z = xp[2 * 16384];
    v.w = xp[3 * 16384];
    reinterpret_cast<float4*>(xT)[pid * 16 + cq] = v;
}

// ---------------- kernel WK: w_conv (O,C,3,3) -> wK[o][ct][n][cc] ----------------
__global__ __launch_bounds__(256) void k_wk(const float* __restrict__ w_conv,
                                            float* __restrict__ wK) {
    int idx = blockIdx.x * 256 + threadIdx.x;      // 64*576 = 36864
    if (idx >= 64 * 576) return;
    int o = idx / 576;
    int r = idx % 576;
    int ct = r / 144;
    int r2 = r % 144;
    int n = r2 >> 4;
    int cc = r2 & 15;
    wK[idx] = w_conv[o * 576 + (ct * 16 + cc) * 9 + n];
}

// ---------------- kernel 1: offset conv + depth bilinear + pm ----------------
// block: 256 thr = 64 pixels (row segment) x 4 channel-groups of 16
__global__ __launch_bounds__(256) void k_offset(const float* __restrict__ x,
                                                const float* __restrict__ depth,
                                                const float* __restrict__ w_p,
                                                const float* __restrict__ b_p,
                                                float* __restrict__ pm) {
    __shared__ float part[4 * 64 * 19];
    int tid = threadIdx.x;
    int p = tid & 63;
    int grp = tid >> 6;
    int pb = blockIdx.x * 64;
    int b = pb >> 14;
    int i = (pb & 16383) >> 7;
    int j = (pb & 127) + p;

    float acc[18];
#pragma unroll
    for (int n = 0; n < 18; ++n) acc[n] = 0.f;

    const float* xb = x + (size_t)b * 64 * 16384;
    for (int c = grp * 16; c < grp * 16 + 16; ++c) {
        float xv[9];
#pragma unroll
        for (int di = 0; di < 3; ++di) {
            int ih = i + di - 1;
            bool rok = ((unsigned)ih < 128u);
#pragma unroll
            for (int dj = 0; dj < 3; ++dj) {
                int jw = j + dj - 1;
                bool ok = rok && ((unsigned)jw < 128u);
                xv[di * 3 + dj] = ok ? xb[c * 16384 + ih * 128 + jw] : 0.f;
            }
        }
        const float* wp = w_p + c * 9;
#pragma unroll
        for (int n = 0; n < 18; ++n) {
            const float* wpn = wp + n * 576;
#pragma unroll
            for (int t = 0; t < 9; ++t) acc[n] += wpn[t] * xv[t];
        }
    }
#pragma unroll
    for (int n = 0; n < 18; ++n) part[(grp * 64 + p) * 19 + n] = acc[n];
    __syncthreads();

    if (tid < 64) {
        float off[18];
#pragma unroll
        for (int n = 0; n < 18; ++n) {
            off[n] = b_p[n] + part[p * 19 + n] + part[(64 + p) * 19 + n] +
                     part[(128 + p) * 19 + n] + part[(192 + p) * 19 + n];
        }
        const float* db = depth + b * 16384;
        float dctr = db[i * 128 + j];
        float* pmo = pm + (size_t)(pb + p) * 27;
#pragma unroll
        for (int n = 0; n < 9; ++n) {
            float p1x = off[n]     + (float)(n / 3 - 1) + (float)(i + 1);
            float p1y = off[9 + n] + (float)(n % 3 - 1) + (float)(j + 1);
            // depth bilinear: clip bounds [0, 127] (reference passes Hc=H), padded lookup
            float fx = floorf(p1x), fy = floorf(p1y);
            float qltx = fminf(fmaxf(fx, 0.f), 127.f);
            float qlty = fminf(fmaxf(fy, 0.f), 127.f);
            float qrbx = fminf(fmaxf(fx + 1.f, 0.f), 127.f);
            float qrby = fminf(fmaxf(fy + 1.f, 0.f), 127.f);
            float pxc = fminf(fmaxf(p1x, 0.f), 127.f);
            float pyc = fminf(fmaxf(p1y, 0.f), 127.f);
            float glt = (1.f + (qltx - pxc)) * (1.f + (qlty - pyc));
            float grb = (1.f - (qrbx - pxc)) * (1.f - (qrby - pyc));
            float glb = (1.f + (qltx - pxc)) * (1.f - (qrby - pyc));
            float grt = (1.f - (qrbx - pxc)) * (1.f + (qlty - pyc));
            int ilx = (int)qltx, ily = (int)qlty, irx = (int)qrbx, iry = (int)qrby;
            auto dv = [&](int qx, int qy) -> float {
                return (qx >= 1 && qx <= 128 && qy >= 1 && qy <= 128)
                           ? db[(qx - 1) * 128 + (qy - 1)] : 0.f;
            };
            float dof = glt * dv(ilx, ily) + grb * dv(irx, iry) +
                        glb * dv(ilx, iry) + grt * dv(irx, ily);
            float dd = fabsf(dctr - dof);
            float dwn = expf(-4.f * dd) + 0.25f;
            float mn  = expf(-dd);
            float p2x = off[n] * dwn     + (float)(n / 3 - 1) + (float)(i + 1);
            float p2y = off[9 + n] * dwn + (float)(n % 3 - 1) + (float)(j + 1);
            pmo[n * 3 + 0] = p2x;
            pmo[n * 3 + 1] = p2y;
            pmo[n * 3 + 2] = mn;
        }
    }
}

// ---------------- kernel 2: gather + GEMM-like reduction ----------------
// block: 256 thr, 64 pixels x 64 out channels, thread tile 4o x 4p, K tiled by 16 ch
__global__ __launch_bounds__(256) void k_main(const float* __restrict__ xT,
                                              const float* __restrict__ wK,
                                              const float* __restrict__ pm,
                                              float* __restrict__ out) {
    __shared__ float ldsX[64 * STR];
    __shared__ float ldsW[64 * STR];
    int tid = threadIdx.x;
    int pb = blockIdx.x * 64;
    int b = pb >> 14;
    int i = (pb & 16383) >> 7;
    int j0 = pb & 127;
    int oi = tid & 15;
    int pi = tid >> 4;  // 0..15

    float acc[4][4];
#pragma unroll
    for (int a = 0; a < 4; ++a)
#pragma unroll
        for (int q = 0; q < 4; ++q) acc[a][q] = 0.f;

    const float* xTb = xT + (size_t)b * 16384 * 64;

    for (int ct = 0; ct < 4; ++ct) {
        __syncthreads();  // protect LDS from previous iter's readers
        // --- gather phase: 64p x 9n x 4ccq float4 samples = 2304 units ---
#pragma unroll
        for (int r = 0; r < 9; ++r) {
            int u = tid + r * 256;
            int ccq = u & 3;
            int t = u >> 2;
            int n = t % 9;
            int p = t / 9;
            const float* pmp = pm + (size_t)(pb + p) * 27 + n * 3;
            float px = pmp[0], py = pmp[1], m = pmp[2];
            // x bilinear: clip bounds [0, 129] (padded dims), padded lookup
            float fx = floorf(px), fy = floorf(py);
            float qltx = fminf(fmaxf(fx, 0.f), 129.f);
            float qlty = fminf(fmaxf(fy, 0.f), 129.f);
            float qrbx = fminf(fmaxf(fx + 1.f, 0.f), 129.f);
            float qrby = fminf(fmaxf(fy + 1.f, 0.f), 129.f);
            float pxc = fminf(fmaxf(px, 0.f), 129.f);
            float pyc = fminf(fmaxf(py, 0.f), 129.f);
            float glt = (1.f + (qltx - pxc)) * (1.f + (qlty - pyc));
            float grb = (1.f - (qrbx - pxc)) * (1.f - (qrby - pyc));
            float glb = (1.f + (qltx - pxc)) * (1.f - (qrby - pyc));
            float grt = (1.f - (qrbx - pxc)) * (1.f + (qlty - pyc));
            int ilx = (int)qltx, ily = (int)qlty, irx = (int)qrbx, iry = (int)qrby;
            int cbase = ct * 16 + ccq * 4;
            auto tap = [&](int qx, int qy) -> float4 {
                if (qx >= 1 && qx <= 128 && qy >= 1 && qy <= 128) {
                    return *reinterpret_cast<const float4*>(
                        &xTb[(size_t)((qx - 1) * 128 + (qy - 1)) * 64 + cbase]);
                }
                return make_float4(0.f, 0.f, 0.f, 0.f);
            };
            float4 vlt = tap(ilx, ily);
            float4 vrb = tap(irx, iry);
            float4 vlb = tap(ilx, iry);
            float4 vrt = tap(irx, ily);
            float4 res;
            res.x = m * (glt * vlt.x + grb * vrb.x + glb * vlb.x + grt * vrt.x);
            res.y = m * (glt * vlt.y + grb * vrb.y + glb * vlb.y + grt * vrt.y);
            res.z = m * (glt * vlt.z + grb * vrb.z + glb * vlb.z + grt * vrt.z);
            res.w = m * (glt * vlt.w + grb * vrb.w + glb * vlb.w + grt * vrt.w);
            *reinterpret_cast<float4*>(&ldsX[p * STR + n * 16 + ccq * 4]) = res;
        }
        // --- stage w tile: 64o x 36 float4 ---
#pragma unroll
        for (int r = 0; r < 9; ++r) {
            int s = tid + r * 256;
            int o = s / 36;
            int kq = s % 36;
            float4 wv = reinterpret_cast<const float4*>(wK)[o * 144 + ct * 36 + kq];
            *reinterpret_cast<float4*>(&ldsW[o * STR + kq * 4]) = wv;
        }
        __syncthreads();
        // --- compute: 36 k-quads, 4o x 4p register tile ---
        for (int kq = 0; kq < 36; ++kq) {
            float4 wv[4], xv[4];
#pragma unroll
            for (int a = 0; a < 4; ++a)
                wv[a] = *reinterpret_cast<const float4*>(&ldsW[(oi + a * 16) * STR + kq * 4]);
#pragma unroll
            for (int q = 0; q < 4; ++q)
                xv[q] = *reinterpret_cast<const float4*>(&ldsX[(pi + q * 16) * STR + kq * 4]);
#pragma unroll
            for (int a = 0; a < 4; ++a)
#pragma unroll
                for (int q = 0; q < 4; ++q) {
                    acc[a][q] += wv[a].x * xv[q].x;
                    acc[a][q] += wv[a].y * xv[q].y;
                    acc[a][q] += wv[a].z * xv[q].z;
                    acc[a][q] += wv[a].w * xv[q].w;
                }
        }
    }
    // --- output: stage through LDS for coalesced stores ---
    __syncthreads();
    float* obuf = ldsW;  // reuse; 64*65 floats
#pragma unroll
    for (int a = 0; a < 4; ++a)
#pragma unroll
        for (int q = 0; q < 4; ++q)
            obuf[(oi + a * 16) * 65 + (pi + q * 16)] = acc[a][q];
    __syncthreads();
#pragma unroll
    for (int r = 0; r < 16; ++r) {
        int idx = tid + r * 256;
        int o = idx >> 6;
        int p = idx & 63;
        out[(size_t)((b * 64 + o) * 128 + i) * 128 + j0 + p] = obuf[o * 65 + p];
    }
}

extern "C" void kernel_launch(void* const* d_in, const int* in_sizes, int n_in,
                              void* d_out, int out_size, void* d_ws, size_t ws_size,
                              hipStream_t stream) {
    (void)in_sizes; (void)n_in; (void)out_size; (void)ws_size;
    const float* x      = (const float*)d_in[0];
    const float* depth  = (const float*)d_in[1];
    const float* w_p    = (const float*)d_in[2];
    const float* b_p    = (const float*)d_in[3];
    const float* w_conv = (const float*)d_in[4];
    float* out = (float*)d_out;
    float* ws = (float*)d_ws;

    float* xT = ws;                          // 2,097,152 floats
    float* wK = ws + 2097152;                // 36,864 floats
    float* pm = ws + 2097152 + 36864;        // 884,736 floats

    hipLaunchKernelGGL(k_transpose, dim3(2048), dim3(256), 0, stream, x, xT);
    hipLaunchKernelGGL(k_wk,        dim3(144),  dim3(256), 0, stream, w_conv, wK);
    hipLaunchKernelGGL(k_offset,    dim3(512),  dim3(256), 0, stream, x, depth, w_p, b_p, pm);
    hipLaunchKernelGGL(k_main,      dim3(512),  dim3(256), 0, stream, xT, wK, pm, out);
}

// Round 3
// 61.182 us; speedup vs baseline: 2.5671x; 2.5671x over previous
//
#include <hip/hip_runtime.h>
#include <math.h>

// B=2, C=64, H=W=128, N=9. Main GEMM: out[o,p] = sum_{k=n*64+c} wK[o,k]*xs[k,p],
// xs = m * bilinear(xT_bf16, p2). Offset GEMM (precision-critical, drives sample
// positions across the reference's depth-bilinear discontinuity at coord 127):
// computed in split-bf16 (3-term) MFMA => fp32-grade offsets.
// MFMA 16x16x32 bf16; A and B packed with the SAME (h=lane>>4,e)->k map so any
// hardware k-permutation cancels. C/D: col=lane&15, row=(lane>>4)*4+reg (verified).

typedef __attribute__((ext_vector_type(8))) short bf16x8;
typedef __attribute__((ext_vector_type(4))) float f32x4;

#define MFMA16(a, b, c) __builtin_amdgcn_mfma_f32_16x16x32_bf16((a), (b), (c), 0, 0, 0)

__device__ __forceinline__ float bf2f(short v) {
    return __uint_as_float(((unsigned)(unsigned short)v) << 16);
}
__device__ __forceinline__ short f2bf(float f) {
    unsigned u = __float_as_uint(f);
    u = u + 0x7fffu + ((u >> 16) & 1u);
    return (short)(u >> 16);
}

// ---------------- x (B,C,H,W) f32 -> xT (B,H*W,C) bf16 (main-gather operand) ----------------
__global__ __launch_bounds__(256) void k_transpose(const float* __restrict__ x,
                                                   short* __restrict__ xT) {
    int idx = blockIdx.x * 256 + threadIdx.x;   // ((b*8+oc)*16384 + pix), 262144 total
    int pix = idx & 16383;
    int oc  = (idx >> 14) & 7;
    int b   = idx >> 17;
    const float* xp = x + (size_t)(b * 64 + oc * 8) * 16384 + pix;
    union { short s[8]; bf16x8 v; } r;
#pragma unroll
    for (int q = 0; q < 8; ++q) r.s[q] = f2bf(xp[q * 16384]);
    *reinterpret_cast<bf16x8*>(xT + ((size_t)(b * 16384 + pix) * 64 + oc * 8)) = r.v;
}

// ---------------- pack w_conv -> wK (bf16), w_p -> wPh/wPl (split bf16) ----------------
// wK[s][h][o][e] = w_conv[o, c, n], k = s*32+h*8+e, n=k/64, c=k%64   (36864 elems)
// wP*[s][h][m][e] = split(w_p[m, c, t]) (m<18 else 0), k=s*32+h*8+e, t=k/64, c=k%64 (18432)
__global__ __launch_bounds__(256) void k_wk(const float* __restrict__ w_conv,
                                            const float* __restrict__ w_p,
                                            short* __restrict__ wK,
                                            short* __restrict__ wPh,
                                            short* __restrict__ wPl) {
    int idx = blockIdx.x * 256 + threadIdx.x;   // 55296 total
    if (idx < 36864) {
        int e = idx & 7, o = (idx >> 3) & 63, h = (idx >> 9) & 3, s = idx >> 11;
        int k = s * 32 + h * 8 + e;
        int n = k >> 6, c = k & 63;
        wK[idx] = f2bf(w_conv[o * 576 + c * 9 + n]);
    } else {
        int j = idx - 36864;
        int e = j & 7, m = (j >> 3) & 31, h = (j >> 8) & 3, s = j >> 10;
        int k = s * 32 + h * 8 + e;
        int t = k >> 6, c = k & 63;
        float v = (m < 18) ? w_p[m * 576 + c * 9 + t] : 0.f;
        short hi = f2bf(v);
        wPh[j] = hi;
        wPl[j] = f2bf(v - bf2f(hi));
    }
}

// ---------------- offset conv (split-bf16 3-term MFMA) + depth bilinear -> pm ----------------
// block = 64-pixel row segment. K-tile ct = source row (i+ct-1), taps dj=0..2.
__global__ __launch_bounds__(256, 2) void k_offset(const float* __restrict__ x,
                                                   const float* __restrict__ depth,
                                                   const short* __restrict__ wPh,
                                                   const short* __restrict__ wPl,
                                                   const float* __restrict__ b_p,
                                                   float* __restrict__ pm) {
    __shared__ float rowbuf[3 * 64 * 66];   // [di][c][col], 50688 B
    __shared__ float offs[64 * 20];         // 5120 B
    int tid = threadIdx.x;
    int lane = tid & 63;
    int wv = tid >> 6;
    int l15 = lane & 15, h = lane >> 4;
    int pb = blockIdx.x << 6;
    int b = pb >> 14, i = (pb & 16383) >> 7, j0 = pb & 127;
    const float* xb = x + (size_t)b * 64 * 16384;

    // stage 3 source rows x 64 ch x 66 cols (fp32, coalesced 66-runs)
    for (int u = tid; u < 3 * 64 * 66; u += 256) {
        int col = u % 66;
        int rc = u / 66;
        int di = rc >> 6, c = rc & 63;
        int si = i + di - 1;
        int sj = j0 + col - 1;
        float v = 0.f;
        if ((unsigned)si < 128u && (unsigned)sj < 128u)
            v = xb[c * 16384 + si * 128 + sj];
        rowbuf[u] = v;
    }
    __syncthreads();

    f32x4 acc0 = {0.f, 0.f, 0.f, 0.f}, acc1 = {0.f, 0.f, 0.f, 0.f};
    for (int ct = 0; ct < 3; ++ct) {
#pragma unroll
        for (int sl = 0; sl < 6; ++sl) {
            int kb = sl * 32 + h * 8;          // within-tile k base
            int tloc = kb >> 6;                // dj
            int c0 = kb & 63;                  // channel base (mult of 8)
            int col = wv * 16 + l15 + tloc;
            union { short s[8]; bf16x8 v; } bh, bl;
#pragma unroll
            for (int e = 0; e < 8; ++e) {
                float f = rowbuf[(ct * 64 + c0 + e) * 66 + col];
                short hi = f2bf(f);
                bh.s[e] = hi;
                bl.s[e] = f2bf(f - bf2f(hi));
            }
            int s = ct * 6 + sl;
            bf16x8 ah0 = *reinterpret_cast<const bf16x8*>(wPh + (size_t)((s * 4 + h) * 32 + l15) * 8);
            bf16x8 ah1 = *reinterpret_cast<const bf16x8*>(wPh + (size_t)((s * 4 + h) * 32 + 16 + l15) * 8);
            bf16x8 al0 = *reinterpret_cast<const bf16x8*>(wPl + (size_t)((s * 4 + h) * 32 + l15) * 8);
            bf16x8 al1 = *reinterpret_cast<const bf16x8*>(wPl + (size_t)((s * 4 + h) * 32 + 16 + l15) * 8);
            acc0 = MFMA16(ah0, bh.v, acc0);
            acc1 = MFMA16(ah1, bh.v, acc1);
            acc0 = MFMA16(ah0, bl.v, acc0);
            acc1 = MFMA16(ah1, bl.v, acc1);
            acc0 = MFMA16(al0, bh.v, acc0);
            acc1 = MFMA16(al1, bh.v, acc1);
        }
    }
    // offs[p][o] = D + bias
    {
        int p = wv * 16 + l15;
#pragma unroll
        for (int r = 0; r < 4; ++r) {
            int o = h * 4 + r;
            if (o < 18) offs[p * 20 + o] = acc0[r] + b_p[o];
            int o1 = 16 + h * 4 + r;
            if (o1 < 18) offs[p * 20 + o1] = acc1[r] + b_p[o1];
        }
    }
    __syncthreads();
    // epilogue: per (p, n) depth bilinear -> pm = {p2x, p2y, m}  (exact reference semantics)
    const float* db = depth + b * 16384;
    int p = tid & 63;
    int g = tid >> 6;
    float dctr = db[i * 128 + j0 + p];
    for (int n = g; n < 9; n += 4) {
        float offx = offs[p * 20 + n];
        float offy = offs[p * 20 + 9 + n];
        float gx = (float)(n / 3 - 1 + i + 1);
        float gy = (float)(n % 3 - 1 + j0 + p + 1);
        float p1x = offx + gx, p1y = offy + gy;
        float fx = floorf(p1x), fy = floorf(p1y);
        float qltx = fminf(fmaxf(fx, 0.f), 127.f);
        float qlty = fminf(fmaxf(fy, 0.f), 127.f);
        float qrbx = fminf(fmaxf(fx + 1.f, 0.f), 127.f);
        float qrby = fminf(fmaxf(fy + 1.f, 0.f), 127.f);
        float pxc = fminf(fmaxf(p1x, 0.f), 127.f);
        float pyc = fminf(fmaxf(p1y, 0.f), 127.f);
        float glt = (1.f + (qltx - pxc)) * (1.f + (qlty - pyc));
        float grb = (1.f - (qrbx - pxc)) * (1.f - (qrby - pyc));
        float glb = (1.f + (qltx - pxc)) * (1.f - (qrby - pyc));
        float grt = (1.f - (qrbx - pxc)) * (1.f + (qlty - pyc));
        int ilx = (int)qltx, ily = (int)qlty, irx = (int)qrbx, iry = (int)qrby;
        auto dv = [&](int qx, int qy) -> float {
            return (qx >= 1 && qx <= 128 && qy >= 1 && qy <= 128) ? db[(qx - 1) * 128 + (qy - 1)] : 0.f;
        };
        float dof = glt * dv(ilx, ily) + grb * dv(irx, iry) + glb * dv(ilx, iry) + grt * dv(irx, ily);
        float dd = fabsf(dctr - dof);
        float dwn = expf(-4.f * dd) + 0.25f;
        float mn = expf(-dd);
        float* dst = pm + ((size_t)(pb + p) * 9 + n) * 3;
        dst[0] = offx * dwn + gx;
        dst[1] = offy * dwn + gy;
        dst[2] = mn;
    }
}

// ---------------- main: gather (bilinear bf16 taps, fp32 combine) -> LDS -> MFMA GEMM ----------------
__global__ __launch_bounds__(256, 3) void k_main(const short* __restrict__ xT,
                                                 const short* __restrict__ wK,
                                                 const float* __restrict__ pm,
                                                 float* __restrict__ out) {
    __shared__ short xs[64 * 200];      // [p][kloc pad 200] bf16, 25600 B
    __shared__ float pmw[576 * 8];      // [(p*9+n)][w0..w3, off0..off3(int bits)], 18432 B
    int tid = threadIdx.x;
    int lane = tid & 63;
    int wv = tid >> 6;
    int l15 = lane & 15, h = lane >> 4;
    int pb = blockIdx.x << 6;
    int b = pb >> 14, i = (pb & 16383) >> 7, j0 = pb & 127;
    const short* xTb = xT + ((size_t)b << 20);

    // --- build per-(p,n) bilinear weights (x m) + corner pixel offsets, once ---
    for (int u = tid; u < 576; u += 256) {
        int p = u / 9, n = u % 9;
        const float* s = pm + ((size_t)(pb + p) * 9 + n) * 3;
        float px = s[0], py = s[1], m = s[2];
        float fx = floorf(px), fy = floorf(py);
        float qltx = fminf(fmaxf(fx, 0.f), 129.f);
        float qlty = fminf(fmaxf(fy, 0.f), 129.f);
        float qrbx = fminf(fmaxf(fx + 1.f, 0.f), 129.f);
        float qrby = fminf(fmaxf(fy + 1.f, 0.f), 129.f);
        float pxc = fminf(fmaxf(px, 0.f), 129.f);
        float pyc = fminf(fmaxf(py, 0.f), 129.f);
        float glt = (1.f + (qltx - pxc)) * (1.f + (qlty - pyc));
        float grb = (1.f - (qrbx - pxc)) * (1.f - (qrby - pyc));
        float glb = (1.f + (qltx - pxc)) * (1.f - (qrby - pyc));
        float grt = (1.f - (qrbx - pxc)) * (1.f + (qlty - pyc));
        int ilx = (int)qltx, ily = (int)qlty, irx = (int)qrbx, iry = (int)qrby;
        float* d = &pmw[u * 8];
        auto mk = [&](int qx, int qy, float gw, int slot) {
            bool ok = (qx >= 1 && qx <= 128 && qy >= 1 && qy <= 128);
            d[slot] = ok ? gw * m : 0.f;
            d[slot + 4] = __int_as_float(ok ? ((qx - 1) * 128 + (qy - 1)) : 0);
        };
        mk(ilx, ily, glt, 0);
        mk(irx, iry, grb, 1);
        mk(ilx, iry, glb, 2);
        mk(irx, ily, grt, 3);
    }

    f32x4 acc0 = {0.f, 0.f, 0.f, 0.f}, acc1 = {0.f, 0.f, 0.f, 0.f};
    f32x4 acc2 = {0.f, 0.f, 0.f, 0.f}, acc3 = {0.f, 0.f, 0.f, 0.f};

    for (int ct = 0; ct < 3; ++ct) {
        __syncthreads();
        // A-frags for this tile (block-invariant, L2 broadcast)
        bf16x8 af[6];
#pragma unroll
        for (int sl = 0; sl < 6; ++sl)
            af[sl] = *reinterpret_cast<const bf16x8*>(
                wK + (size_t)(((ct * 6 + sl) * 4 + h) * 64 + wv * 16 + l15) * 8);
        // gather: units (p, nloc, o8); o8 fastest across lanes -> contiguous 128B taps
#pragma unroll
        for (int r = 0; r < 6; ++r) {
            int u = (r << 8) + tid;
            int o8 = u & 7;
            int t2 = u >> 3;
            int nloc = t2 % 3;
            int p = t2 / 3;
            const float* wsrc = &pmw[(p * 9 + ct * 3 + nloc) * 8];
            float4 w4 = *reinterpret_cast<const float4*>(wsrc);
            float4 o4 = *reinterpret_cast<const float4*>(wsrc + 4);
            const short* bp = xTb + o8 * 8;
            bf16x8 t0 = *reinterpret_cast<const bf16x8*>(bp + ((size_t)__float_as_int(o4.x) << 6));
            bf16x8 t1 = *reinterpret_cast<const bf16x8*>(bp + ((size_t)__float_as_int(o4.y) << 6));
            bf16x8 t2v = *reinterpret_cast<const bf16x8*>(bp + ((size_t)__float_as_int(o4.z) << 6));
            bf16x8 t3 = *reinterpret_cast<const bf16x8*>(bp + ((size_t)__float_as_int(o4.w) << 6));
            union { short s[8]; bf16x8 v; } res;
#pragma unroll
            for (int c = 0; c < 8; ++c) {
                float f = w4.x * bf2f(t0[c]) + w4.y * bf2f(t1[c]) +
                          w4.z * bf2f(t2v[c]) + w4.w * bf2f(t3[c]);
                res.s[c] = f2bf(f);
            }
            *reinterpret_cast<bf16x8*>(&xs[p * 200 + nloc * 64 + o8 * 8]) = res.v;
        }
        __syncthreads();
        // compute: wave wv = o-tile, 4 p-tiles
#pragma unroll
        for (int sl = 0; sl < 6; ++sl) {
            int ko = sl * 32 + h * 8;
            bf16x8 b0 = *reinterpret_cast<const bf16x8*>(&xs[(l15) * 200 + ko]);
            bf16x8 b1 = *reinterpret_cast<const bf16x8*>(&xs[(l15 + 16) * 200 + ko]);
            bf16x8 b2 = *reinterpret_cast<const bf16x8*>(&xs[(l15 + 32) * 200 + ko]);
            bf16x8 b3 = *reinterpret_cast<const bf16x8*>(&xs[(l15 + 48) * 200 + ko]);
            acc0 = MFMA16(af[sl], b0, acc0);
            acc1 = MFMA16(af[sl], b1, acc1);
            acc2 = MFMA16(af[sl], b2, acc2);
            acc3 = MFMA16(af[sl], b3, acc3);
        }
    }
    // --- output: stage through LDS (reuse xs) for coalesced stores ---
    __syncthreads();
    float* obuf = reinterpret_cast<float*>(xs);   // 64o x 66p f32 = 16896 B
    int ob = wv * 16 + h * 4;
#pragma unroll
    for (int r = 0; r < 4; ++r) {
        obuf[(ob + r) * 66 + l15] = acc0[r];
        obuf[(ob + r) * 66 + l15 + 16] = acc1[r];
        obuf[(ob + r) * 66 + l15 + 32] = acc2[r];
        obuf[(ob + r) * 66 + l15 + 48] = acc3[r];
    }
    __syncthreads();
#pragma unroll
    for (int r = 0; r < 16; ++r) {
        int u = (r << 8) + tid;
        int o = u >> 6, p = u & 63;
        out[(size_t)(b * 64 + o) * 16384 + i * 128 + j0 + p] = obuf[o * 66 + p];
    }
}

extern "C" void kernel_launch(void* const* d_in, const int* in_sizes, int n_in,
                              void* d_out, int out_size, void* d_ws, size_t ws_size,
                              hipStream_t stream) {
    (void)in_sizes; (void)n_in; (void)out_size; (void)ws_size;
    const float* x      = (const float*)d_in[0];
    const float* depth  = (const float*)d_in[1];
    const float* w_p    = (const float*)d_in[2];
    const float* b_p    = (const float*)d_in[3];
    const float* w_conv = (const float*)d_in[4];
    float* out = (float*)d_out;

    char* wsb = (char*)d_ws;
    short* xT  = (short*)wsb;                      // 4,194,304 B
    short* wK  = (short*)(wsb + 4194304);          //    73,728 B
    short* wPh = (short*)(wsb + 4268032);          //    36,864 B
    short* wPl = (short*)(wsb + 4304896);          //    36,864 B
    float* pm  = (float*)(wsb + 4341760);          // 3,538,944 B  (total ~7.88 MB)

    hipLaunchKernelGGL(k_transpose, dim3(1024), dim3(256), 0, stream, x, xT);
    hipLaunchKernelGGL(k_wk,        dim3(216),  dim3(256), 0, stream, w_conv, w_p, wK, wPh, wPl);
    hipLaunchKernelGGL(k_offset,    dim3(512),  dim3(256), 0, stream, x, depth, wPh, wPl, b_p, pm);
    hipLaunchKernelGGL(k_main,      dim3(512),  dim3(256), 0, stream, xT, wK, pm, out);
}

// Round 4
// 50.897 us; speedup vs baseline: 3.0858x; 1.2021x over previous
//
#include <hip/hip_runtime.h>
#include <math.h>

// B=2, C=64, H=W=128, N=9, KS=3, PAD=1.
// Fully fused per-wave design: each 64-thread block = one wave = 16 output pixels.
//   Phase 1: offset conv via split-bf16 (hi/lo) 3-term MFMA  -> fp32-grade offsets
//            (precision-critical: offsets cross the reference's depth-bilinear
//             discontinuity at coord 127; plain bf16 failed round 2).
//   Epilogue: depth bilinear -> modulated positions p2 + m -> per-(p,n) x-bilinear
//             weights (x m) + corner indices in LDS (pmw).
//   Phase 2: register-direct gather: lane (p=l&15, h=l>>4) builds the MFMA
//            B-fragment for its pixel/channel-chunk from 4 bf16x8 taps; 4 MFMA
//            per k-slice accumulate all 64 out-channels. No barriers, no xs LDS.
// k map (shared by A and B operands, so any HW k-permutation cancels):
//   k = s*32 + h*8 + e;  tap t = s>>1 (phase1) / sample n = s>>1 (phase2);
//   c = (s&1)*32 + h*8 + e.
// C/D: col = lane&15 (pixel), row = h*4+reg (out-channel within 16-tile). Verified r3.

typedef __attribute__((ext_vector_type(8))) short bf16x8;
typedef __attribute__((ext_vector_type(4))) float f32x4;

#define MFMA16(a, b, c) __builtin_amdgcn_mfma_f32_16x16x32_bf16((a), (b), (c), 0, 0, 0)

__device__ __forceinline__ float bf2f(short v) {
    return __uint_as_float(((unsigned)(unsigned short)v) << 16);
}
__device__ __forceinline__ short f2bf(float f) {
    unsigned u = __float_as_uint(f);
    u = u + 0x7fffu + ((u >> 16) & 1u);
    return (short)(u >> 16);
}

// ---------------- prep: x -> xT/xTlo (B,H*W,C) bf16 pair; pack wK, wPh, wPl ----------------
__global__ __launch_bounds__(256) void k_prep(const float* __restrict__ x,
                                              const float* __restrict__ w_conv,
                                              const float* __restrict__ w_p,
                                              short* __restrict__ xT,
                                              short* __restrict__ xTlo,
                                              short* __restrict__ wK,
                                              short* __restrict__ wPh,
                                              short* __restrict__ wPl) {
    int bid = blockIdx.x;
    int tid = threadIdx.x;
    if (bid < 1024) {
        int idx = bid * 256 + tid;            // ((b*8+oc)*16384 + pix)
        int pix = idx & 16383;
        int oc  = (idx >> 14) & 7;
        int b   = idx >> 17;
        const float* xp = x + (size_t)(b * 64 + oc * 8) * 16384 + pix;
        union { short s[8]; bf16x8 v; } hi, lo;
#pragma unroll
        for (int q = 0; q < 8; ++q) {
            float f = xp[q * 16384];
            short hb = f2bf(f);
            hi.s[q] = hb;
            lo.s[q] = f2bf(f - bf2f(hb));
        }
        size_t o = (size_t)(b * 16384 + pix) * 64 + oc * 8;
        *reinterpret_cast<bf16x8*>(xT + o)   = hi.v;
        *reinterpret_cast<bf16x8*>(xTlo + o) = lo.v;
    } else {
        int idx = (bid - 1024) * 256 + tid;   // < 55296
        if (idx >= 55296) return;
        if (idx < 36864) {
            // wK[s][h][o][e] = w_conv[o, c, n]; k=s*32+h*8+e, n=k/64, c=k%64
            int e = idx & 7, o = (idx >> 3) & 63, h = (idx >> 9) & 3, s = idx >> 11;
            int k = s * 32 + h * 8 + e;
            int n = k >> 6, c = k & 63;
            wK[idx] = f2bf(w_conv[o * 576 + c * 9 + n]);
        } else {
            // wP*[s][h][m][e] = split(w_p[m, c, t]); k=s*32+h*8+e, t=k/64, c=k%64
            int j = idx - 36864;
            int e = j & 7, m = (j >> 3) & 31, h = (j >> 8) & 3, s = j >> 10;
            int k = s * 32 + h * 8 + e;
            int t = k >> 6, c = k & 63;
            float v = (m < 18) ? w_p[m * 576 + c * 9 + t] : 0.f;
            short hb = f2bf(v);
            wPh[j] = hb;
            wPl[j] = f2bf(v - bf2f(hb));
        }
    }
}

// ---------------- fused: offset conv + epilogue + gather-GEMM, 1 wave / 16 px ----------------
__global__ __launch_bounds__(64, 4) void k_fused(const short* __restrict__ xT,
                                                 const short* __restrict__ xTlo,
                                                 const short* __restrict__ wPh,
                                                 const short* __restrict__ wPl,
                                                 const short* __restrict__ wK,
                                                 const float* __restrict__ depth,
                                                 const float* __restrict__ b_p,
                                                 float* __restrict__ out) {
    __shared__ float offs[16 * 20];     // [p][o<18]       1280 B
    __shared__ float pmw[16 * 9 * 8];   // [(p*9+n)][w0..3, idx0..3]  4608 B
    __shared__ float obuf[64 * 17];     // [o][p pad]      4352 B
    int lane = threadIdx.x;
    int l15 = lane & 15, h = lane >> 4;
    int pb = blockIdx.x << 4;                       // 16-px tile
    int b = pb >> 14, i = (pb & 16383) >> 7, j0 = pb & 127;
    const short* xTb  = xT   + ((size_t)b << 20);
    const short* xTlb = xTlo + ((size_t)b << 20);

    // ---- phase 1: offset conv, split-bf16 3-term MFMA ----
    f32x4 acc0 = {0.f, 0.f, 0.f, 0.f}, acc1 = {0.f, 0.f, 0.f, 0.f};
    for (int s = 0; s < 18; ++s) {
        int t = s >> 1;
        int c0 = ((s & 1) << 5) + (h << 3);
        int si = i + t / 3 - 1;
        int sj = j0 + l15 + t % 3 - 1;
        bf16x8 bh = {0, 0, 0, 0, 0, 0, 0, 0};
        bf16x8 bl = {0, 0, 0, 0, 0, 0, 0, 0};
        if ((unsigned)si < 128u && (unsigned)sj < 128u) {
            size_t o = (size_t)(si * 128 + sj) * 64 + c0;
            bh = *reinterpret_cast<const bf16x8*>(xTb + o);
            bl = *reinterpret_cast<const bf16x8*>(xTlb + o);
        }
        const short* wh = wPh + (size_t)((s * 4 + h) * 32 + l15) * 8;
        const short* wl = wPl + (size_t)((s * 4 + h) * 32 + l15) * 8;
        bf16x8 ah0 = *reinterpret_cast<const bf16x8*>(wh);
        bf16x8 ah1 = *reinterpret_cast<const bf16x8*>(wh + 128);
        bf16x8 al0 = *reinterpret_cast<const bf16x8*>(wl);
        bf16x8 al1 = *reinterpret_cast<const bf16x8*>(wl + 128);
        acc0 = MFMA16(ah0, bh, acc0);
        acc1 = MFMA16(ah1, bh, acc1);
        acc0 = MFMA16(ah0, bl, acc0);
        acc1 = MFMA16(ah1, bl, acc1);
        acc0 = MFMA16(al0, bh, acc0);
        acc1 = MFMA16(al1, bh, acc1);
    }
#pragma unroll
    for (int r = 0; r < 4; ++r) {
        int o = h * 4 + r;
        offs[l15 * 20 + o] = acc0[r] + b_p[o];
        int o1 = 16 + h * 4 + r;
        if (o1 < 18) offs[l15 * 20 + o1] = acc1[r] + b_p[o1];
    }
    __syncthreads();

    // ---- epilogue: depth bilinear -> pmw (weights x m + corner indices) ----
    const float* db = depth + (b << 14);
    float dctr = db[(i << 7) + j0 + l15];
    for (int n = h; n < 9; n += 4) {
        float offx = offs[l15 * 20 + n];
        float offy = offs[l15 * 20 + 9 + n];
        float gx = (float)(n / 3 - 1 + i + 1);
        float gy = (float)(n % 3 - 1 + j0 + l15 + 1);
        float p1x = offx + gx, p1y = offy + gy;
        // depth bilinear: clip [0,127], valid lookup [1,128] (exact reference semantics)
        float fx = floorf(p1x), fy = floorf(p1y);
        float qltx = fminf(fmaxf(fx, 0.f), 127.f);
        float qlty = fminf(fmaxf(fy, 0.f), 127.f);
        float qrbx = fminf(fmaxf(fx + 1.f, 0.f), 127.f);
        float qrby = fminf(fmaxf(fy + 1.f, 0.f), 127.f);
        float pxc = fminf(fmaxf(p1x, 0.f), 127.f);
        float pyc = fminf(fmaxf(p1y, 0.f), 127.f);
        float glt = (1.f + (qltx - pxc)) * (1.f + (qlty - pyc));
        float grb = (1.f - (qrbx - pxc)) * (1.f - (qrby - pyc));
        float glb = (1.f + (qltx - pxc)) * (1.f - (qrby - pyc));
        float grt = (1.f - (qrbx - pxc)) * (1.f + (qlty - pyc));
        int ilx = (int)qltx, ily = (int)qlty, irx = (int)qrbx, iry = (int)qrby;
        auto dv = [&](int qx, int qy) -> float {
            return (qx >= 1 && qx <= 128 && qy >= 1 && qy <= 128) ? db[(qx - 1) * 128 + (qy - 1)] : 0.f;
        };
        float dof = glt * dv(ilx, ily) + grb * dv(irx, iry) + glb * dv(ilx, iry) + grt * dv(irx, ily);
        float dd = fabsf(dctr - dof);
        float dwn = expf(-4.f * dd) + 0.25f;
        float mn = expf(-dd);
        float px = offx * dwn + gx;
        float py = offy * dwn + gy;
        // x bilinear: clip [0,129], valid lookup [1,128]
        float fx2 = floorf(px), fy2 = floorf(py);
        float xltx = fminf(fmaxf(fx2, 0.f), 129.f);
        float xlty = fminf(fmaxf(fy2, 0.f), 129.f);
        float xrbx = fminf(fmaxf(fx2 + 1.f, 0.f), 129.f);
        float xrby = fminf(fmaxf(fy2 + 1.f, 0.f), 129.f);
        float xpxc = fminf(fmaxf(px, 0.f), 129.f);
        float xpyc = fminf(fmaxf(py, 0.f), 129.f);
        float wlt = (1.f + (xltx - xpxc)) * (1.f + (xlty - xpyc));
        float wrb = (1.f - (xrbx - xpxc)) * (1.f - (xrby - xpyc));
        float wlb = (1.f + (xltx - xpxc)) * (1.f - (xrby - xpyc));
        float wrt = (1.f - (xrbx - xpxc)) * (1.f + (xlty - xpyc));
        int jlx = (int)xltx, jly = (int)xlty, jrx = (int)xrbx, jry = (int)xrby;
        float* d = &pmw[(l15 * 9 + n) * 8];
        auto mk = [&](int qx, int qy, float gw, int slot) {
            bool ok = (qx >= 1 && qx <= 128 && qy >= 1 && qy <= 128);
            d[slot] = ok ? gw * mn : 0.f;
            d[slot + 4] = __int_as_float(ok ? ((qx - 1) * 128 + (qy - 1)) : 0);
        };
        mk(jlx, jly, wlt, 0);
        mk(jrx, jry, wrb, 1);
        mk(jlx, jry, wlb, 2);
        mk(jrx, jly, wrt, 3);
    }
    __syncthreads();

    // ---- phase 2: register-direct gather -> MFMA over 64 out-channels ----
    f32x4 A0 = {0.f, 0.f, 0.f, 0.f}, A1 = {0.f, 0.f, 0.f, 0.f};
    f32x4 A2 = {0.f, 0.f, 0.f, 0.f}, A3 = {0.f, 0.f, 0.f, 0.f};
    for (int n = 0; n < 9; ++n) {
        const float* ww = &pmw[(l15 * 9 + n) * 8];
        float4 w4 = *reinterpret_cast<const float4*>(ww);
        int4 o4 = *reinterpret_cast<const int4*>(ww + 4);
        const short* bp0 = xTb + ((size_t)o4.x << 6);
        const short* bp1 = xTb + ((size_t)o4.y << 6);
        const short* bp2 = xTb + ((size_t)o4.z << 6);
        const short* bp3 = xTb + ((size_t)o4.w << 6);
#pragma unroll
        for (int half = 0; half < 2; ++half) {
            int c0 = (half << 5) + (h << 3);
            bf16x8 t0 = *reinterpret_cast<const bf16x8*>(bp0 + c0);
            bf16x8 t1 = *reinterpret_cast<const bf16x8*>(bp1 + c0);
            bf16x8 t2 = *reinterpret_cast<const bf16x8*>(bp2 + c0);
            bf16x8 t3 = *reinterpret_cast<const bf16x8*>(bp3 + c0);
            union { short s[8]; bf16x8 v; } bf;
#pragma unroll
            for (int e = 0; e < 8; ++e) {
                float f = w4.x * bf2f(t0[e]) + w4.y * bf2f(t1[e]) +
                          w4.z * bf2f(t2[e]) + w4.w * bf2f(t3[e]);
                bf.s[e] = f2bf(f);
            }
            int s = n * 2 + half;
            const short* wkp = wK + (size_t)((s * 4 + h) * 64 + l15) * 8;
            bf16x8 af0 = *reinterpret_cast<const bf16x8*>(wkp);
            bf16x8 af1 = *reinterpret_cast<const bf16x8*>(wkp + 128);
            bf16x8 af2 = *reinterpret_cast<const bf16x8*>(wkp + 256);
            bf16x8 af3 = *reinterpret_cast<const bf16x8*>(wkp + 384);
            A0 = MFMA16(af0, bf.v, A0);
            A1 = MFMA16(af1, bf.v, A1);
            A2 = MFMA16(af2, bf.v, A2);
            A3 = MFMA16(af3, bf.v, A3);
        }
    }

    // ---- store: LDS transpose -> 4x64B segments per iteration ----
#pragma unroll
    for (int r = 0; r < 4; ++r) {
        obuf[(h * 4 + r) * 17 + l15]        = A0[r];
        obuf[(16 + h * 4 + r) * 17 + l15]   = A1[r];
        obuf[(32 + h * 4 + r) * 17 + l15]   = A2[r];
        obuf[(48 + h * 4 + r) * 17 + l15]   = A3[r];
    }
    __syncthreads();
#pragma unroll
    for (int r = 0; r < 16; ++r) {
        int o = r * 4 + h;
        out[((size_t)(b * 64 + o) << 14) + (i << 7) + j0 + l15] = obuf[o * 17 + l15];
    }
}

extern "C" void kernel_launch(void* const* d_in, const int* in_sizes, int n_in,
                              void* d_out, int out_size, void* d_ws, size_t ws_size,
                              hipStream_t stream) {
    (void)in_sizes; (void)n_in; (void)out_size; (void)ws_size;
    const float* x      = (const float*)d_in[0];
    const float* depth  = (const float*)d_in[1];
    const float* w_p    = (const float*)d_in[2];
    const float* b_p    = (const float*)d_in[3];
    const float* w_conv = (const float*)d_in[4];
    float* out = (float*)d_out;

    char* wsb = (char*)d_ws;
    short* xT   = (short*)wsb;                     // 4,194,304 B
    short* xTlo = (short*)(wsb + 4194304);         // 4,194,304 B
    short* wK   = (short*)(wsb + 8388608);         //    73,728 B
    short* wPh  = (short*)(wsb + 8462336);         //    36,864 B
    short* wPl  = (short*)(wsb + 8499200);         //    36,864 B  (total ~8.54 MB)

    hipLaunchKernelGGL(k_prep,  dim3(1240), dim3(256), 0, stream,
                       x, w_conv, w_p, xT, xTlo, wK, wPh, wPl);
    hipLaunchKernelGGL(k_fused, dim3(2048), dim3(64), 0, stream,
                       xT, xTlo, wPh, wPl, wK, depth, b_p, out);
}

// Round 5
// 48.611 us; speedup vs baseline: 3.2309x; 1.0470x over previous
//
#include <hip/hip_runtime.h>
#include <math.h>

// B=2, C=64, H=W=128, N=9, KS=3, PAD=1.
// Round 5: split-K 2-wave blocks (same 16 px) + XCD band swizzle.
//   Phase 1 (offset conv, split-bf16 3-term MFMA for fp32-grade offsets):
//     wave w covers channel half c in [32w, 32w+32) for all 9 taps; partial
//     18-channel sums reduced in LDS.
//   Epilogue: depth bilinear -> per-(p,n) x-bilinear weights (x m) + corner
//     indices (pmw), split across the 8 (wave,h) groups.
//   Phase 2 (gather-GEMM): wave w covers samples n%2==w; lane (p=l&15,h=l>>4)
//     builds the MFMA B-fragment in registers from 4 bf16x8 taps; final
//     accumulator reduce via LDS.
// k map (shared by A and B packs, so any HW k-permutation cancels):
//   k = s*32 + h*8 + e;  t/n = s>>1;  c = (s&1)*32 + h*8 + e.
// C/D: col = lane&15 (pixel), row = h*4+reg (out-channel in 16-tile). Verified r3/r4.

typedef __attribute__((ext_vector_type(8))) short bf16x8;
typedef __attribute__((ext_vector_type(4))) float f32x4;

#define MFMA16(a, b, c) __builtin_amdgcn_mfma_f32_16x16x32_bf16((a), (b), (c), 0, 0, 0)

__device__ __forceinline__ float bf2f(short v) {
    return __uint_as_float(((unsigned)(unsigned short)v) << 16);
}
__device__ __forceinline__ short f2bf(float f) {
    unsigned u = __float_as_uint(f);
    u = u + 0x7fffu + ((u >> 16) & 1u);
    return (short)(u >> 16);
}

// ---------------- prep: x -> xT/xTlo (B,H*W,C) bf16 pair; pack wK, wPh, wPl ----------------
__global__ __launch_bounds__(256) void k_prep(const float* __restrict__ x,
                                              const float* __restrict__ w_conv,
                                              const float* __restrict__ w_p,
                                              short* __restrict__ xT,
                                              short* __restrict__ xTlo,
                                              short* __restrict__ wK,
                                              short* __restrict__ wPh,
                                              short* __restrict__ wPl) {
    int bid = blockIdx.x;
    int tid = threadIdx.x;
    if (bid < 1024) {
        int idx = bid * 256 + tid;            // ((b*8+oc)*16384 + pix)
        int pix = idx & 16383;
        int oc  = (idx >> 14) & 7;
        int b   = idx >> 17;
        const float* xp = x + (size_t)(b * 64 + oc * 8) * 16384 + pix;
        union { short s[8]; bf16x8 v; } hi, lo;
#pragma unroll
        for (int q = 0; q < 8; ++q) {
            float f = xp[q * 16384];
            short hb = f2bf(f);
            hi.s[q] = hb;
            lo.s[q] = f2bf(f - bf2f(hb));
        }
        size_t o = (size_t)(b * 16384 + pix) * 64 + oc * 8;
        *reinterpret_cast<bf16x8*>(xT + o)   = hi.v;
        *reinterpret_cast<bf16x8*>(xTlo + o) = lo.v;
    } else {
        int idx = (bid - 1024) * 256 + tid;   // < 55296
        if (idx >= 55296) return;
        if (idx < 36864) {
            // wK[s][h][o][e] = w_conv[o, c, n]; k=s*32+h*8+e, n=k/64, c=k%64
            int e = idx & 7, o = (idx >> 3) & 63, h = (idx >> 9) & 3, s = idx >> 11;
            int k = s * 32 + h * 8 + e;
            int n = k >> 6, c = k & 63;
            wK[idx] = f2bf(w_conv[o * 576 + c * 9 + n]);
        } else {
            // wP*[s][h][m][e] = split(w_p[m, c, t]); k=s*32+h*8+e, t=k/64, c=k%64
            int j = idx - 36864;
            int e = j & 7, m = (j >> 3) & 31, h = (j >> 8) & 3, s = j >> 10;
            int k = s * 32 + h * 8 + e;
            int t = k >> 6, c = k & 63;
            float v = (m < 18) ? w_p[m * 576 + c * 9 + t] : 0.f;
            short hb = f2bf(v);
            wPh[j] = hb;
            wPl[j] = f2bf(v - bf2f(hb));
        }
    }
}

// ---------------- fused: 128 thr = 2 waves cooperating on 16 px (split-K) ----------------
__global__ __launch_bounds__(128, 4) void k_fused(const short* __restrict__ xT,
                                                  const short* __restrict__ xTlo,
                                                  const short* __restrict__ wPh,
                                                  const short* __restrict__ wPl,
                                                  const short* __restrict__ wK,
                                                  const float* __restrict__ depth,
                                                  const float* __restrict__ b_p,
                                                  float* __restrict__ out) {
    __shared__ float part1[2][16][20];   // per-wave offset-conv partials   2560 B
    __shared__ float offs[16][20];       // reduced offsets                 1280 B
    __shared__ float pmw[144][8];        // [(p*9+n)][w0..3, idx0..3]       4608 B
    __shared__ float accred[64][20];     // wave1 phase-2 partials          5120 B
    __shared__ float obuf[64 * 17];      // store transpose                 4352 B
    int tid = threadIdx.x;
    int lane = tid & 63;
    int wv = tid >> 6;                   // 0 / 1
    int l15 = lane & 15, h = lane >> 4;
    // XCD band swizzle: 2048 blocks, 8 XCDs -> each XCD owns a contiguous
    // 4096-px band (2 image rows); tap working set ~150 KB => L2-resident.
    int bid = blockIdx.x;
    int swz = (bid & 7) * 256 + (bid >> 3);
    int pb = swz << 4;                   // 16-px tile
    int b = pb >> 14, i = (pb & 16383) >> 7, j0 = pb & 127;
    const short* xTb  = xT   + ((size_t)b << 20);
    const short* xTlb = xTlo + ((size_t)b << 20);

    // ---- phase 1: offset conv; wave wv covers channel half wv ----
    f32x4 acc0 = {0.f, 0.f, 0.f, 0.f}, acc1 = {0.f, 0.f, 0.f, 0.f};
    int c0p = (wv << 5) + (h << 3);
    for (int t = 0; t < 9; ++t) {
        int s = t * 2 + wv;
        int si = i + t / 3 - 1;
        int sj = j0 + l15 + t % 3 - 1;
        bf16x8 bh = {0, 0, 0, 0, 0, 0, 0, 0};
        bf16x8 bl = {0, 0, 0, 0, 0, 0, 0, 0};
        if ((unsigned)si < 128u && (unsigned)sj < 128u) {
            size_t o = (size_t)(si * 128 + sj) * 64 + c0p;
            bh = *reinterpret_cast<const bf16x8*>(xTb + o);
            bl = *reinterpret_cast<const bf16x8*>(xTlb + o);
        }
        const short* wh = wPh + (size_t)((s * 4 + h) * 32 + l15) * 8;
        const short* wl = wPl + (size_t)((s * 4 + h) * 32 + l15) * 8;
        bf16x8 ah0 = *reinterpret_cast<const bf16x8*>(wh);
        bf16x8 ah1 = *reinterpret_cast<const bf16x8*>(wh + 128);
        bf16x8 al0 = *reinterpret_cast<const bf16x8*>(wl);
        bf16x8 al1 = *reinterpret_cast<const bf16x8*>(wl + 128);
        acc0 = MFMA16(ah0, bh, acc0);
        acc1 = MFMA16(ah1, bh, acc1);
        acc0 = MFMA16(ah0, bl, acc0);
        acc1 = MFMA16(ah1, bl, acc1);
        acc0 = MFMA16(al0, bh, acc0);
        acc1 = MFMA16(al1, bh, acc1);
    }
#pragma unroll
    for (int r = 0; r < 4; ++r) {
        part1[wv][l15][h * 4 + r] = acc0[r];
        int o1 = 16 + h * 4 + r;
        if (o1 < 18) part1[wv][l15][o1] = acc1[r];
    }
    __syncthreads();
    // reduce partials + bias -> offs (288 entries, 128 threads)
    for (int u = tid; u < 288; u += 128) {
        int p = u / 18, o = u % 18;
        offs[p][o] = part1[0][p][o] + part1[1][p][o] + b_p[o];
    }
    __syncthreads();

    // ---- epilogue: depth bilinear -> pmw; 8 (wave,h) groups over 9 samples ----
    const float* db = depth + (b << 14);
    float dctr = db[(i << 7) + j0 + l15];
    int g = (wv << 2) + h;
    for (int n = g; n < 9; n += 8) {
        float offx = offs[l15][n];
        float offy = offs[l15][9 + n];
        float gx = (float)(n / 3 - 1 + i + 1);
        float gy = (float)(n % 3 - 1 + j0 + l15 + 1);
        float p1x = offx + gx, p1y = offy + gy;
        // depth bilinear: clip [0,127], valid lookup [1,128] (exact ref semantics)
        float fx = floorf(p1x), fy = floorf(p1y);
        float qltx = fminf(fmaxf(fx, 0.f), 127.f);
        float qlty = fminf(fmaxf(fy, 0.f), 127.f);
        float qrbx = fminf(fmaxf(fx + 1.f, 0.f), 127.f);
        float qrby = fminf(fmaxf(fy + 1.f, 0.f), 127.f);
        float pxc = fminf(fmaxf(p1x, 0.f), 127.f);
        float pyc = fminf(fmaxf(p1y, 0.f), 127.f);
        float glt = (1.f + (qltx - pxc)) * (1.f + (qlty - pyc));
        float grb = (1.f - (qrbx - pxc)) * (1.f - (qrby - pyc));
        float glb = (1.f + (qltx - pxc)) * (1.f - (qrby - pyc));
        float grt = (1.f - (qrbx - pxc)) * (1.f + (qlty - pyc));
        int ilx = (int)qltx, ily = (int)qlty, irx = (int)qrbx, iry = (int)qrby;
        auto dv = [&](int qx, int qy) -> float {
            return (qx >= 1 && qx <= 128 && qy >= 1 && qy <= 128) ? db[(qx - 1) * 128 + (qy - 1)] : 0.f;
        };
        float dof = glt * dv(ilx, ily) + grb * dv(irx, iry) + glb * dv(ilx, iry) + grt * dv(irx, ily);
        float dd = fabsf(dctr - dof);
        float dwn = expf(-4.f * dd) + 0.25f;
        float mn = expf(-dd);
        float px = offx * dwn + gx;
        float py = offy * dwn + gy;
        // x bilinear: clip [0,129], valid lookup [1,128]
        float fx2 = floorf(px), fy2 = floorf(py);
        float xltx = fminf(fmaxf(fx2, 0.f), 129.f);
        float xlty = fminf(fmaxf(fy2, 0.f), 129.f);
        float xrbx = fminf(fmaxf(fx2 + 1.f, 0.f), 129.f);
        float xrby = fminf(fmaxf(fy2 + 1.f, 0.f), 129.f);
        float xpxc = fminf(fmaxf(px, 0.f), 129.f);
        float xpyc = fminf(fmaxf(py, 0.f), 129.f);
        float wlt = (1.f + (xltx - xpxc)) * (1.f + (xlty - xpyc));
        float wrb = (1.f - (xrbx - xpxc)) * (1.f - (xrby - xpyc));
        float wlb = (1.f + (xltx - xpxc)) * (1.f - (xrby - xpyc));
        float wrt = (1.f - (xrbx - xpxc)) * (1.f + (xlty - xpyc));
        int jlx = (int)xltx, jly = (int)xlty, jrx = (int)xrbx, jry = (int)xrby;
        float* d = pmw[l15 * 9 + n];
        auto mk = [&](int qx, int qy, float gw, int slot) {
            bool ok = (qx >= 1 && qx <= 128 && qy >= 1 && qy <= 128);
            d[slot] = ok ? gw * mn : 0.f;
            d[slot + 4] = __int_as_float(ok ? ((qx - 1) * 128 + (qy - 1)) : 0);
        };
        mk(jlx, jly, wlt, 0);
        mk(jrx, jry, wrb, 1);
        mk(jlx, jry, wlb, 2);
        mk(jrx, jly, wrt, 3);
    }
    __syncthreads();

    // ---- phase 2: gather-GEMM; wave wv covers samples n%2==wv ----
    f32x4 A0 = {0.f, 0.f, 0.f, 0.f}, A1 = {0.f, 0.f, 0.f, 0.f};
    f32x4 A2 = {0.f, 0.f, 0.f, 0.f}, A3 = {0.f, 0.f, 0.f, 0.f};
    for (int n = wv; n < 9; n += 2) {
        const float* ww = pmw[l15 * 9 + n];
        float4 w4 = *reinterpret_cast<const float4*>(ww);
        int4 o4 = *reinterpret_cast<const int4*>(ww + 4);
        const short* bp0 = xTb + ((size_t)o4.x << 6);
        const short* bp1 = xTb + ((size_t)o4.y << 6);
        const short* bp2 = xTb + ((size_t)o4.z << 6);
        const short* bp3 = xTb + ((size_t)o4.w << 6);
#pragma unroll
        for (int half = 0; half < 2; ++half) {
            int c0 = (half << 5) + (h << 3);
            bf16x8 t0 = *reinterpret_cast<const bf16x8*>(bp0 + c0);
            bf16x8 t1 = *reinterpret_cast<const bf16x8*>(bp1 + c0);
            bf16x8 t2 = *reinterpret_cast<const bf16x8*>(bp2 + c0);
            bf16x8 t3 = *reinterpret_cast<const bf16x8*>(bp3 + c0);
            union { short s[8]; bf16x8 v; } bf;
#pragma unroll
            for (int e = 0; e < 8; ++e) {
                float f = w4.x * bf2f(t0[e]) + w4.y * bf2f(t1[e]) +
                          w4.z * bf2f(t2[e]) + w4.w * bf2f(t3[e]);
                bf.s[e] = f2bf(f);
            }
            int s = n * 2 + half;
            const short* wkp = wK + (size_t)((s * 4 + h) * 64 + l15) * 8;
            bf16x8 af0 = *reinterpret_cast<const bf16x8*>(wkp);
            bf16x8 af1 = *reinterpret_cast<const bf16x8*>(wkp + 128);
            bf16x8 af2 = *reinterpret_cast<const bf16x8*>(wkp + 256);
            bf16x8 af3 = *reinterpret_cast<const bf16x8*>(wkp + 384);
            A0 = MFMA16(af0, bf.v, A0);
            A1 = MFMA16(af1, bf.v, A1);
            A2 = MFMA16(af2, bf.v, A2);
            A3 = MFMA16(af3, bf.v, A3);
        }
    }
    // ---- reduce across waves + store ----
    if (wv == 1) {
        float* ar = accred[lane];
        *reinterpret_cast<f32x4*>(ar)      = A0;
        *reinterpret_cast<f32x4*>(ar + 4)  = A1;
        *reinterpret_cast<f32x4*>(ar + 8)  = A2;
        *reinterpret_cast<f32x4*>(ar + 12) = A3;
    }
    __syncthreads();
    if (wv == 0) {
        const float* ar = accred[lane];
#pragma unroll
        for (int r = 0; r < 4; ++r) {
            obuf[(h * 4 + r) * 17 + l15]      = A0[r] + ar[r];
            obuf[(16 + h * 4 + r) * 17 + l15] = A1[r] + ar[4 + r];
            obuf[(32 + h * 4 + r) * 17 + l15] = A2[r] + ar[8 + r];
            obuf[(48 + h * 4 + r) * 17 + l15] = A3[r] + ar[12 + r];
        }
    }
    __syncthreads();
#pragma unroll
    for (int r = 0; r < 8; ++r) {
        int u = (r << 7) + tid;
        int o = u >> 4, p = u & 15;
        out[((size_t)(b * 64 + o) << 14) + (i << 7) + j0 + p] = obuf[o * 17 + p];
    }
}

extern "C" void kernel_launch(void* const* d_in, const int* in_sizes, int n_in,
                              void* d_out, int out_size, void* d_ws, size_t ws_size,
                              hipStream_t stream) {
    (void)in_sizes; (void)n_in; (void)out_size; (void)ws_size;
    const float* x      = (const float*)d_in[0];
    const float* depth  = (const float*)d_in[1];
    const float* w_p    = (const float*)d_in[2];
    const float* b_p    = (const float*)d_in[3];
    const float* w_conv = (const float*)d_in[4];
    float* out = (float*)d_out;

    char* wsb = (char*)d_ws;
    short* xT   = (short*)wsb;                     // 4,194,304 B
    short* xTlo = (short*)(wsb + 4194304);         // 4,194,304 B
    short* wK   = (short*)(wsb + 8388608);         //    73,728 B
    short* wPh  = (short*)(wsb + 8462336);         //    36,864 B
    short* wPl  = (short*)(wsb + 8499200);         //    36,864 B  (total ~8.54 MB)

    hipLaunchKernelGGL(k_prep,  dim3(1240), dim3(256), 0, stream,
                       x, w_conv, w_p, xT, xTlo, wK, wPh, wPl);
    hipLaunchKernelGGL(k_fused, dim3(2048), dim3(128), 0, stream,
                       xT, xTlo, wPh, wPl, wK, depth, b_p, out);
}

// Round 6
// 46.229 us; speedup vs baseline: 3.3974x; 1.0515x over previous
//
#include <hip/hip_runtime.h>
#include <math.h>

// B=2, C=64, H=W=128, N=9, KS=3, PAD=1.
// Round 6: r5 structure (split-K 2-wave blocks + XCD band swizzle) with
//   - software-pipelined phase 2 (depth-1 double buffer, static reg names)
//   - prefetch-all phase 1 (all 18 hi/lo tap loads in flight)
//   - LDS-transpose k_prep (coalesced 4KB store runs)
// Offset conv stays split-bf16 3-term MFMA (fp32-grade offsets; the reference's
// depth bilinear is discontinuous at coord 127 and amplifies offset error).
// k map (same for A and B packs, so HW k-permutation cancels):
//   k = s*32 + h*8 + e;  t/n = s>>1;  c = (s&1)*32 + h*8 + e.
// C/D: col = lane&15 (pixel), row = h*4+reg. Verified r3-r5.

typedef __attribute__((ext_vector_type(8))) short bf16x8;
typedef __attribute__((ext_vector_type(4))) short s16x4;
typedef __attribute__((ext_vector_type(4))) float f32x4;

#define MFMA16(a, b, c) __builtin_amdgcn_mfma_f32_16x16x32_bf16((a), (b), (c), 0, 0, 0)

__device__ __forceinline__ float bf2f(short v) {
    return __uint_as_float(((unsigned)(unsigned short)v) << 16);
}
__device__ __forceinline__ short f2bf(float f) {
    unsigned u = __float_as_uint(f);
    u = u + 0x7fffu + ((u >> 16) & 1u);
    return (short)(u >> 16);
}

// ---------------- prep: LDS-transpose x -> xT/xTlo; pack wK, wPh, wPl ----------------
__global__ __launch_bounds__(256) void k_prep(const float* __restrict__ x,
                                              const float* __restrict__ w_conv,
                                              const float* __restrict__ w_p,
                                              short* __restrict__ xT,
                                              short* __restrict__ xTlo,
                                              short* __restrict__ wK,
                                              short* __restrict__ wPh,
                                              short* __restrict__ wPl) {
    __shared__ short sH[128][72];   // 18,432 B (row stride 144B, 16B aligned)
    __shared__ short sL[128][72];   // 18,432 B
    int bid = blockIdx.x;
    int tid = threadIdx.x;
    if (bid < 256) {
        // transpose 128 px x 64 ch
        int p = tid & 127;
        int halfc = tid >> 7;           // 0/1
        int pix0 = bid << 7;            // global pixel base; b = pix0>>14
        int b = pix0 >> 14;
        const float* xb = x + (size_t)b * 64 * 16384 + (pix0 & 16383);
#pragma unroll
        for (int cc = 0; cc < 8; ++cc) {
            int c0 = cc * 8 + halfc * 4;
            union { short s[4]; s16x4 v; } hi, lo;
#pragma unroll
            for (int e = 0; e < 4; ++e) {
                float v = xb[(c0 + e) * 16384 + p];
                short hb = f2bf(v);
                hi.s[e] = hb;
                lo.s[e] = f2bf(v - bf2f(hb));
            }
            *reinterpret_cast<s16x4*>(&sH[p][c0]) = hi.v;
            *reinterpret_cast<s16x4*>(&sL[p][c0]) = lo.v;
        }
        __syncthreads();
        short* xTo = xT   + ((size_t)pix0 << 6);
        short* xLo = xTlo + ((size_t)pix0 << 6);
#pragma unroll
        for (int r = 0; r < 4; ++r) {
            int u = (r << 8) + tid;
            int pp = u >> 3, ch8 = u & 7;
            *reinterpret_cast<bf16x8*>(xTo + pp * 64 + ch8 * 8) =
                *reinterpret_cast<const bf16x8*>(&sH[pp][ch8 * 8]);
            *reinterpret_cast<bf16x8*>(xLo + pp * 64 + ch8 * 8) =
                *reinterpret_cast<const bf16x8*>(&sL[pp][ch8 * 8]);
        }
    } else {
        int idx = (bid - 256) * 256 + tid;   // < 55296
        if (idx >= 55296) return;
        if (idx < 36864) {
            // wK[s][h][o][e] = w_conv[o, c, n]; k=s*32+h*8+e, n=k/64, c=k%64
            int e = idx & 7, o = (idx >> 3) & 63, h = (idx >> 9) & 3, s = idx >> 11;
            int k = s * 32 + h * 8 + e;
            int n = k >> 6, c = k & 63;
            wK[idx] = f2bf(w_conv[o * 576 + c * 9 + n]);
        } else {
            // wP*[s][h][m][e] = split(w_p[m, c, t]); k=s*32+h*8+e, t=k/64, c=k%64
            int j = idx - 36864;
            int e = j & 7, m = (j >> 3) & 31, h = (j >> 8) & 3, s = j >> 10;
            int k = s * 32 + h * 8 + e;
            int t = k >> 6, c = k & 63;
            float v = (m < 18) ? w_p[m * 576 + c * 9 + t] : 0.f;
            short hb = f2bf(v);
            wPh[j] = hb;
            wPl[j] = f2bf(v - bf2f(hb));
        }
    }
}

// phase-2 helper macros (static register names; parity of buffer is compile-time)
#define LD_SAMPLE(n, W4, T0, T1, T2, T3, T4, T5, T6, T7)              \
    {                                                                 \
        const float* ww_ = pmw[l15 * 9 + (n)];                        \
        W4 = *reinterpret_cast<const float4*>(ww_);                   \
        int4 o4_ = *reinterpret_cast<const int4*>(ww_ + 4);           \
        const short* q0_ = xTb + ((size_t)o4_.x << 6) + (h << 3);     \
        const short* q1_ = xTb + ((size_t)o4_.y << 6) + (h << 3);     \
        const short* q2_ = xTb + ((size_t)o4_.z << 6) + (h << 3);     \
        const short* q3_ = xTb + ((size_t)o4_.w << 6) + (h << 3);     \
        T0 = *reinterpret_cast<const bf16x8*>(q0_);                   \
        T1 = *reinterpret_cast<const bf16x8*>(q1_);                   \
        T2 = *reinterpret_cast<const bf16x8*>(q2_);                   \
        T3 = *reinterpret_cast<const bf16x8*>(q3_);                   \
        T4 = *reinterpret_cast<const bf16x8*>(q0_ + 32);              \
        T5 = *reinterpret_cast<const bf16x8*>(q1_ + 32);              \
        T6 = *reinterpret_cast<const bf16x8*>(q2_ + 32);              \
        T7 = *reinterpret_cast<const bf16x8*>(q3_ + 32);              \
    }

#define DO_SAMPLE(n, W4, T0, T1, T2, T3, T4, T5, T6, T7)              \
    {                                                                 \
        union { short s[8]; bf16x8 v; } f0_, f1_;                     \
        _Pragma("unroll")                                             \
        for (int e = 0; e < 8; ++e) {                                 \
            f0_.s[e] = f2bf(W4.x * bf2f(T0[e]) + W4.y * bf2f(T1[e]) + \
                            W4.z * bf2f(T2[e]) + W4.w * bf2f(T3[e])); \
            f1_.s[e] = f2bf(W4.x * bf2f(T4[e]) + W4.y * bf2f(T5[e]) + \
                            W4.z * bf2f(T6[e]) + W4.w * bf2f(T7[e])); \
        }                                                             \
        const short* wk0_ = wK + (size_t)((((n) * 8) + h) * 64 + l15) * 8; \
        const short* wk1_ = wk0_ + 2048;                              \
        A0 = MFMA16(*reinterpret_cast<const bf16x8*>(wk0_),       f0_.v, A0); \
        A1 = MFMA16(*reinterpret_cast<const bf16x8*>(wk0_ + 128), f0_.v, A1); \
        A2 = MFMA16(*reinterpret_cast<const bf16x8*>(wk0_ + 256), f0_.v, A2); \
        A3 = MFMA16(*reinterpret_cast<const bf16x8*>(wk0_ + 384), f0_.v, A3); \
        A0 = MFMA16(*reinterpret_cast<const bf16x8*>(wk1_),       f1_.v, A0); \
        A1 = MFMA16(*reinterpret_cast<const bf16x8*>(wk1_ + 128), f1_.v, A1); \
        A2 = MFMA16(*reinterpret_cast<const bf16x8*>(wk1_ + 256), f1_.v, A2); \
        A3 = MFMA16(*reinterpret_cast<const bf16x8*>(wk1_ + 384), f1_.v, A3); \
    }

// ---------------- fused: 128 thr = 2 waves on 16 px (split-K), pipelined ----------------
__global__ __launch_bounds__(128, 4) void k_fused(const short* __restrict__ xT,
                                                  const short* __restrict__ xTlo,
                                                  const short* __restrict__ wPh,
                                                  const short* __restrict__ wPl,
                                                  const short* __restrict__ wK,
                                                  const float* __restrict__ depth,
                                                  const float* __restrict__ b_p,
                                                  float* __restrict__ out) {
    __shared__ float part1[2][16][20];   // 2560 B
    __shared__ float offs[16][20];       // 1280 B
    __shared__ float pmw[144][8];        // 4608 B
    __shared__ float accred[64][16];     // 4096 B
    __shared__ float obuf[64 * 17];      // 4352 B   (total ~16.9 KB)
    int tid = threadIdx.x;
    int lane = tid & 63;
    int wv = tid >> 6;
    int l15 = lane & 15, h = lane >> 4;
    // XCD band swizzle: each XCD owns a contiguous 2-row pixel band
    int bid = blockIdx.x;
    int swz = (bid & 7) * 256 + (bid >> 3);
    int pb = swz << 4;
    int b = pb >> 14, i = (pb & 16383) >> 7, j0 = pb & 127;
    const short* xTb  = xT   + ((size_t)b << 20);
    const short* xTlb = xTlo + ((size_t)b << 20);

    // ---- phase 1: offset conv; wave wv = channel half; prefetch all taps ----
    int c0p = (wv << 5) + (h << 3);
    bf16x8 Ph0, Ph1, Ph2, Ph3, Ph4, Ph5, Ph6, Ph7, Ph8;
    bf16x8 Pl0, Pl1, Pl2, Pl3, Pl4, Pl5, Pl6, Pl7, Pl8;
#define LD_TAP(t, VH, VL)                                             \
    {                                                                 \
        int si_ = i + (t) / 3 - 1;                                    \
        int sj_ = j0 + l15 + (t) % 3 - 1;                             \
        VH = (bf16x8){0, 0, 0, 0, 0, 0, 0, 0};                        \
        VL = (bf16x8){0, 0, 0, 0, 0, 0, 0, 0};                        \
        if ((unsigned)si_ < 128u && (unsigned)sj_ < 128u) {           \
            size_t o_ = (size_t)(si_ * 128 + sj_) * 64 + c0p;         \
            VH = *reinterpret_cast<const bf16x8*>(xTb + o_);          \
            VL = *reinterpret_cast<const bf16x8*>(xTlb + o_);         \
        }                                                             \
    }
    LD_TAP(0, Ph0, Pl0) LD_TAP(1, Ph1, Pl1) LD_TAP(2, Ph2, Pl2)
    LD_TAP(3, Ph3, Pl3) LD_TAP(4, Ph4, Pl4) LD_TAP(5, Ph5, Pl5)
    LD_TAP(6, Ph6, Pl6) LD_TAP(7, Ph7, Pl7) LD_TAP(8, Ph8, Pl8)
#undef LD_TAP

    f32x4 acc0 = {0.f, 0.f, 0.f, 0.f}, acc1 = {0.f, 0.f, 0.f, 0.f};
#define P1_TAP(t, VH, VL)                                                         \
    {                                                                             \
        int s_ = (t) * 2 + wv;                                                    \
        const short* wh_ = wPh + (size_t)((s_ * 4 + h) * 32 + l15) * 8;           \
        const short* wl_ = wPl + (size_t)((s_ * 4 + h) * 32 + l15) * 8;           \
        bf16x8 ah0_ = *reinterpret_cast<const bf16x8*>(wh_);                      \
        bf16x8 ah1_ = *reinterpret_cast<const bf16x8*>(wh_ + 128);                \
        bf16x8 al0_ = *reinterpret_cast<const bf16x8*>(wl_);                      \
        bf16x8 al1_ = *reinterpret_cast<const bf16x8*>(wl_ + 128);                \
        acc0 = MFMA16(ah0_, VH, acc0);                                            \
        acc1 = MFMA16(ah1_, VH, acc1);                                            \
        acc0 = MFMA16(ah0_, VL, acc0);                                            \
        acc1 = MFMA16(ah1_, VL, acc1);                                            \
        acc0 = MFMA16(al0_, VH, acc0);                                            \
        acc1 = MFMA16(al1_, VH, acc1);                                            \
    }
    P1_TAP(0, Ph0, Pl0) P1_TAP(1, Ph1, Pl1) P1_TAP(2, Ph2, Pl2)
    P1_TAP(3, Ph3, Pl3) P1_TAP(4, Ph4, Pl4) P1_TAP(5, Ph5, Pl5)
    P1_TAP(6, Ph6, Pl6) P1_TAP(7, Ph7, Pl7) P1_TAP(8, Ph8, Pl8)
#undef P1_TAP

#pragma unroll
    for (int r = 0; r < 4; ++r) {
        part1[wv][l15][h * 4 + r] = acc0[r];
        int o1 = 16 + h * 4 + r;
        if (o1 < 18) part1[wv][l15][o1] = acc1[r];
    }
    __syncthreads();
    for (int u = tid; u < 288; u += 128) {
        int p = u / 18, o = u % 18;
        offs[p][o] = part1[0][p][o] + part1[1][p][o] + b_p[o];
    }
    __syncthreads();

    // ---- epilogue: depth bilinear -> pmw (exact reference semantics) ----
    const float* db = depth + (b << 14);
    float dctr = db[(i << 7) + j0 + l15];
    int g = (wv << 2) + h;
    for (int n = g; n < 9; n += 8) {
        float offx = offs[l15][n];
        float offy = offs[l15][9 + n];
        float gx = (float)(n / 3 - 1 + i + 1);
        float gy = (float)(n % 3 - 1 + j0 + l15 + 1);
        float p1x = offx + gx, p1y = offy + gy;
        float fx = floorf(p1x), fy = floorf(p1y);
        float qltx = fminf(fmaxf(fx, 0.f), 127.f);
        float qlty = fminf(fmaxf(fy, 0.f), 127.f);
        float qrbx = fminf(fmaxf(fx + 1.f, 0.f), 127.f);
        float qrby = fminf(fmaxf(fy + 1.f, 0.f), 127.f);
        float pxc = fminf(fmaxf(p1x, 0.f), 127.f);
        float pyc = fminf(fmaxf(p1y, 0.f), 127.f);
        float glt = (1.f + (qltx - pxc)) * (1.f + (qlty - pyc));
        float grb = (1.f - (qrbx - pxc)) * (1.f - (qrby - pyc));
        float glb = (1.f + (qltx - pxc)) * (1.f - (qrby - pyc));
        float grt = (1.f - (qrbx - pxc)) * (1.f + (qlty - pyc));
        int ilx = (int)qltx, ily = (int)qlty, irx = (int)qrbx, iry = (int)qrby;
        auto dv = [&](int qx, int qy) -> float {
            return (qx >= 1 && qx <= 128 && qy >= 1 && qy <= 128) ? db[(qx - 1) * 128 + (qy - 1)] : 0.f;
        };
        float dof = glt * dv(ilx, ily) + grb * dv(irx, iry) + glb * dv(ilx, iry) + grt * dv(irx, ily);
        float dd = fabsf(dctr - dof);
        float dwn = expf(-4.f * dd) + 0.25f;
        float mn = expf(-dd);
        float px = offx * dwn + gx;
        float py = offy * dwn + gy;
        float fx2 = floorf(px), fy2 = floorf(py);
        float xltx = fminf(fmaxf(fx2, 0.f), 129.f);
        float xlty = fminf(fmaxf(fy2, 0.f), 129.f);
        float xrbx = fminf(fmaxf(fx2 + 1.f, 0.f), 129.f);
        float xrby = fminf(fmaxf(fy2 + 1.f, 0.f), 129.f);
        float xpxc = fminf(fmaxf(px, 0.f), 129.f);
        float xpyc = fminf(fmaxf(py, 0.f), 129.f);
        float wlt = (1.f + (xltx - xpxc)) * (1.f + (xlty - xpyc));
        float wrb = (1.f - (xrbx - xpxc)) * (1.f - (xrby - xpyc));
        float wlb = (1.f + (xltx - xpxc)) * (1.f - (xrby - xpyc));
        float wrt = (1.f - (xrbx - xpxc)) * (1.f + (xlty - xpyc));
        int jlx = (int)xltx, jly = (int)xlty, jrx = (int)xrbx, jry = (int)xrby;
        float* d = pmw[l15 * 9 + n];
        auto mk = [&](int qx, int qy, float gw, int slot) {
            bool ok = (qx >= 1 && qx <= 128 && qy >= 1 && qy <= 128);
            d[slot] = ok ? gw * mn : 0.f;
            d[slot + 4] = __int_as_float(ok ? ((qx - 1) * 128 + (qy - 1)) : 0);
        };
        mk(jlx, jly, wlt, 0);
        mk(jrx, jry, wrb, 1);
        mk(jlx, jry, wlb, 2);
        mk(jrx, jly, wrt, 3);
    }
    __syncthreads();

    // ---- phase 2: pipelined gather-GEMM; wave wv covers n%2==wv ----
    f32x4 A0 = {0.f, 0.f, 0.f, 0.f}, A1 = {0.f, 0.f, 0.f, 0.f};
    f32x4 A2 = {0.f, 0.f, 0.f, 0.f}, A3 = {0.f, 0.f, 0.f, 0.f};
    {
        float4 wA, wB;
        bf16x8 a0, a1, a2, a3, a4, a5, a6, a7;
        bf16x8 c0, c1, c2, c3, c4, c5, c6, c7;
        LD_SAMPLE(wv, wA, a0, a1, a2, a3, a4, a5, a6, a7)
        LD_SAMPLE(wv + 2, wB, c0, c1, c2, c3, c4, c5, c6, c7)
        DO_SAMPLE(wv, wA, a0, a1, a2, a3, a4, a5, a6, a7)
        LD_SAMPLE(wv + 4, wA, a0, a1, a2, a3, a4, a5, a6, a7)
        DO_SAMPLE(wv + 2, wB, c0, c1, c2, c3, c4, c5, c6, c7)
        LD_SAMPLE(wv + 6, wB, c0, c1, c2, c3, c4, c5, c6, c7)
        DO_SAMPLE(wv + 4, wA, a0, a1, a2, a3, a4, a5, a6, a7)
        if (wv == 0) {
            LD_SAMPLE(8, wA, a0, a1, a2, a3, a4, a5, a6, a7)
        }
        DO_SAMPLE(wv + 6, wB, c0, c1, c2, c3, c4, c5, c6, c7)
        if (wv == 0) {
            DO_SAMPLE(8, wA, a0, a1, a2, a3, a4, a5, a6, a7)
        }
    }
    // ---- reduce across waves + store ----
    if (wv == 1) {
        float* ar = accred[lane];
        *reinterpret_cast<f32x4*>(ar)      = A0;
        *reinterpret_cast<f32x4*>(ar + 4)  = A1;
        *reinterpret_cast<f32x4*>(ar + 8)  = A2;
        *reinterpret_cast<f32x4*>(ar + 12) = A3;
    }
    __syncthreads();
    if (wv == 0) {
        const float* ar = accred[lane];
#pragma unroll
        for (int r = 0; r < 4; ++r) {
            obuf[(h * 4 + r) * 17 + l15]      = A0[r] + ar[r];
            obuf[(16 + h * 4 + r) * 17 + l15] = A1[r] + ar[4 + r];
            obuf[(32 + h * 4 + r) * 17 + l15] = A2[r] + ar[8 + r];
            obuf[(48 + h * 4 + r) * 17 + l15] = A3[r] + ar[12 + r];
        }
    }
    __syncthreads();
#pragma unroll
    for (int r = 0; r < 8; ++r) {
        int u = (r << 7) + tid;
        int o = u >> 4, p = u & 15;
        out[((size_t)(b * 64 + o) << 14) + (i << 7) + j0 + p] = obuf[o * 17 + p];
    }
}

extern "C" void kernel_launch(void* const* d_in, const int* in_sizes, int n_in,
                              void* d_out, int out_size, void* d_ws, size_t ws_size,
                              hipStream_t stream) {
    (void)in_sizes; (void)n_in; (void)out_size; (void)ws_size;
    const float* x      = (const float*)d_in[0];
    const float* depth  = (const float*)d_in[1];
    const float* w_p    = (const float*)d_in[2];
    const float* b_p    = (const float*)d_in[3];
    const float* w_conv = (const float*)d_in[4];
    float* out = (float*)d_out;

    char* wsb = (char*)d_ws;
    short* xT   = (short*)wsb;                     // 4,194,304 B
    short* xTlo = (short*)(wsb + 4194304);         // 4,194,304 B
    short* wK   = (short*)(wsb + 8388608);         //    73,728 B
    short* wPh  = (short*)(wsb + 8462336);         //    36,864 B
    short* wPl  = (short*)(wsb + 8499200);         //    36,864 B  (total ~8.54 MB)

    hipLaunchKernelGGL(k_prep,  dim3(472),  dim3(256), 0, stream,
                       x, w_conv, w_p, xT, xTlo, wK, wPh, wPl);
    hipLaunchKernelGGL(k_fused, dim3(2048), dim3(128), 0, stream,
                       xT, xTlo, wPh, wPl, wK, depth, b_p, out);
}